// Round 10
// baseline (248.046 us; speedup 1.0000x reference)
//
#include <hip/hip_runtime.h>
#include <hip/hip_bf16.h>

#define SL 2048
#define NK 24
#define NI 256
#define NO 256
#define NB 2
#define NC 48
#define TD 64

typedef __bf16 bf16x8 __attribute__((ext_vector_type(8)));
typedef float f32x4 __attribute__((ext_vector_type(4)));
typedef unsigned short u16x8 __attribute__((ext_vector_type(8)));
typedef unsigned short ushort_t;
typedef unsigned int u32;

// workspace layout (bytes)
// Toeplitz bank: 35 slots (slots 0..2 = zeros for d=-3..-1; slot s=d+3)
#define OFF_T   0ull
#define SZ_T    (35ull*48*64*64*2)
#define OFF_MT  (OFF_T + SZ_T)            // M_T [48][256][256] bf16 ([c][o][i])
#define SZ_MT   (48ull*256*256*2)
#define OFF_XB  (OFF_MT + SZ_MT)          // x bf16 [2][2048][256]
#define SZ_XB   (2ull*2048*256*2)
#define OFF_YT  (OFF_XB + SZ_XB)          // Y_T [2][48][256][2048] bf16 ([b][c][o][t])
#define SZ_YT   (2ull*48*256*2048*2)
#define WS_NEED (OFF_YT + SZ_YT)

__device__ __forceinline__ unsigned short f2bf(float f) {
    unsigned int u = __float_as_uint(f);
    unsigned int r = (u + 0x7FFFu + ((u >> 16) & 1u)) >> 16;
    return (unsigned short)r;
}

__device__ __forceinline__ void glds16(ushort_t* l, const ushort_t* g) {
    __builtin_amdgcn_global_load_lds((const __attribute__((address_space(1))) u32*)g,
                                     (__attribute__((address_space(3))) u32*)l, 16, 0, 0);
}

// ---- kernel P: fused prep (cvt_x | mt | toep), blockIdx-partitioned ------
__global__ __launch_bounds__(256) void k_prep(const float* __restrict__ x,
                                              const float* __restrict__ phi,
                                              const float* __restrict__ Mp,
                                              const float* __restrict__ Mm,
                                              ushort_t* __restrict__ xb,
                                              ushort_t* __restrict__ mt,
                                              ushort_t* __restrict__ T) {
    __shared__ float tile[64][65];
    int blk = blockIdx.x, tid = threadIdx.x;
    if (blk < 1024) {
        int i = blk * 256 + tid;                 // float4 index, 262144 total
        float4 v = reinterpret_cast<const float4*>(x)[i];
        ushort4 o;
        o.x = f2bf(v.x); o.y = f2bf(v.y); o.z = f2bf(v.z); o.w = f2bf(v.w);
        reinterpret_cast<ushort4*>(xb)[i] = o;
    } else if (blk < 1792) {
        int id = blk - 1024;                     // 768 = 48 c x 4 it x 4 ot
        int c = id >> 4, it = (id >> 2) & 3, ot = id & 3;
        int k = c >> 1;
        const float* M = (c & 1) ? Mm : Mp;
        int col = tid & 63, rq = tid >> 6;
        for (int rr = 0; rr < 64; rr += 4) {
            int i = rr + rq;
            tile[i][col] = M[((k * NI) + (it * 64 + i)) * NO + ot * 64 + col];
        }
        __syncthreads();
        for (int rr = 0; rr < 64; rr += 4) {
            int o = rr + rq;
            mt[((c * NO) + (ot * 64 + o)) * NI + it * 64 + col] = f2bf(tile[col][o]);
        }
    } else {
        int orig = (blk - 1792) * 4 + (tid >> 6);   // 1680 = 35 slots x 48 c
        int dblk = orig / 48, c = orig - dblk * 48;
        int d = dblk - 3;
        int ti = tid & 63;
        int k = c >> 1, odd = c & 1;
        for (int li = 0; li < TD; ++li) {
            int s = d * TD + li - ti;
            float v = 0.f;
            if (s >= 0 && s < SL) {
                v = phi[s * NK + k];
                if (odd && (s & 1)) v = -v;
            }
            T[(((dblk) * NC + c) * TD + li) * TD + ti] = f2bf(v);
        }
    }
}

// ---- kernel 2: Y_T[b][c][o][t] = sum_i x[b,t,i] * M_c[i,o] (known-good) --
__global__ __launch_bounds__(256, 4) void k_gemm1(const ushort_t* __restrict__ XB,
                                                  const ushort_t* __restrict__ MT,
                                                  ushort_t* __restrict__ yt) {
    __shared__ ushort_t sh[17408];
    int nb_ = blockIdx.x;
    int rb  = blockIdx.y;
    int n0 = nb_ * 128;
    int tid = threadIdx.x, lane = tid & 63, wid = tid >> 6;
    int wr = wid >> 1, wc = wid & 1;
    int ln15 = lane & 15, lq = lane >> 4;
    int swz = lq ^ ((ln15 >> 1) & 3);

    const ushort_t* Arow = XB + (size_t)(rb * 128) * 256;
    const ushort_t* Brow = MT + (size_t)n0 * 256;

    auto stage = [&](int bufsel, int s) {
        ushort_t* L = sh + bufsel * 8192;
        int k0 = s * 32;
#pragma unroll
        for (int jj = 0; jj < 2; ++jj) {
            int flat = tid + jj * 256;
            int row = flat >> 2;
            int k8s = (flat & 3) ^ ((flat >> 3) & 3);
            glds16(L + flat * 8, Arow + row * 256 + k0 + k8s * 8);
        }
#pragma unroll
        for (int jj = 0; jj < 2; ++jj) {
            int flat = tid + jj * 256;
            int row = flat >> 2;
            int k8s = (flat & 3) ^ ((flat >> 3) & 3);
            glds16(L + 4096 + flat * 8, Brow + row * 256 + k0 + k8s * 8);
        }
    };

    f32x4 acc[4][4];
    f32x4 z = {0.f, 0.f, 0.f, 0.f};
#pragma unroll
    for (int mi = 0; mi < 4; ++mi)
#pragma unroll
        for (int ni = 0; ni < 4; ++ni) acc[mi][ni] = z;

    stage(0, 0);
    __syncthreads();
    for (int s = 0; s < 8; ++s) {
        int cur = s & 1;
        if (s < 7) stage(cur ^ 1, s + 1);
        const ushort_t* Ab = sh + cur * 8192;
        const ushort_t* Bb = Ab + 4096;
        bf16x8 af[4], bfr[4];
#pragma unroll
        for (int mi = 0; mi < 4; ++mi)
            af[mi] = *reinterpret_cast<const bf16x8*>(Ab + (wr * 64 + mi * 16 + ln15) * 32 + swz * 8);
#pragma unroll
        for (int ni = 0; ni < 4; ++ni)
            bfr[ni] = *reinterpret_cast<const bf16x8*>(Bb + (wc * 64 + ni * 16 + ln15) * 32 + swz * 8);
#pragma unroll
        for (int mi = 0; mi < 4; ++mi)
#pragma unroll
            for (int ni = 0; ni < 4; ++ni)
                acc[mi][ni] = __builtin_amdgcn_mfma_f32_16x16x32_bf16(af[mi], bfr[ni], acc[mi][ni], 0, 0, 0);
        __syncthreads();
    }

    ushort_t* OT = sh;  // [128 n][136]
#pragma unroll
    for (int mi = 0; mi < 4; ++mi)
#pragma unroll
        for (int ni = 0; ni < 4; ++ni) {
            int t_loc = wr * 64 + mi * 16 + lq * 4;
            int n_loc = wc * 64 + ni * 16 + ln15;
            ushort4 pk;
            pk.x = f2bf(acc[mi][ni][0]);
            pk.y = f2bf(acc[mi][ni][1]);
            pk.z = f2bf(acc[mi][ni][2]);
            pk.w = f2bf(acc[mi][ni][3]);
            *reinterpret_cast<ushort4*>(OT + n_loc * 136 + t_loc) = pk;
        }
    __syncthreads();
    int b = rb >> 4, t0 = (rb & 15) * 128;
#pragma unroll
    for (int jj = 0; jj < 8; ++jj) {
        int flat = tid + jj * 256;
        int n_loc = flat >> 4, te = (flat & 15) * 8;
        int nn = n0 + n_loc;
        int c = nn >> 8, o = nn & 255;
        *reinterpret_cast<u16x8*>(yt + ((size_t)(b * NC + c) * NO + o) * SL + t0 + te) =
            *reinterpret_cast<const u16x8*>(OT + n_loc * 136 + te);
    }
}

// ---- kernel 3: conv, 128x128-tile, 4 waves, 2 blocks/CU (independent
// barrier domains), round-7 register-dbuf single-barrier schedule.
// LDS 64KB/block: A bufs @0/16KB, B bufs @32KB/48KB.
#define LOAD_SET(SA, SB, SLOT, AB, BB) do {                                        \
    _Pragma("unroll") for (int m = 0; m < 4; ++m)                                  \
        SA[m] = *(const bf16x8*)((AB) + aBase + (SLOT) + m * 2048);                \
    _Pragma("unroll") for (int n2 = 0; n2 < 4; ++n2)                               \
        SB[n2] = *(const bf16x8*)((BB) + bBase + (SLOT) + n2 * 2048);              \
} while (0)

#define MFMA_SET(SA, SB) do {                                                      \
    _Pragma("unroll") for (int m = 0; m < 4; ++m)                                  \
    _Pragma("unroll") for (int n2 = 0; n2 < 4; ++n2)                               \
        acc[m][n2] = __builtin_amdgcn_mfma_f32_16x16x32_bf16(                      \
            SA[m], SB[n2], acc[m][n2], 0, 0, 0);                                   \
} while (0)

__global__ __launch_bounds__(256, 2) void k_conv4(const ushort_t* __restrict__ Tb,
                                                  const ushort_t* __restrict__ yt,
                                                  float* __restrict__ out) {
    __shared__ ushort_t sh[32768];   // 64 KB

    int blk = blockIdx.x;                       // 1024
    int orig = (blk & 7) * 128 + (blk >> 3);    // XCD-chunked bijective (1024%8==0)
    // blocks per (b,ob,pp') group, proportional to pp'+1; sum = 256 per quadrant
    const int NBt[16] = {2, 4, 6, 8, 9, 11, 13, 15, 17, 19, 21, 23, 24, 26, 28, 30};
    int bo = orig >> 8;                         // 4 quadrants (b, ob)
    int b_ = bo >> 1, ob = bo & 1;
    int j = orig & 255;
    int pp = 0, base = 0;
    while (pp < 15 && j >= base + NBt[pp]) { base += NBt[pp]; ++pp; }
    int idx = j - base, n = NBt[pp];
    int U = 96 * (pp + 1);                      // K-units (tt,c) in this group
    int u0 = idx * U / n, u1 = (idx + 1) * U / n;

    int tid = threadIdx.x, lane = tid & 63, wid = tid >> 6;
    int wr = wid >> 1, wc = wid & 1;            // 2M x 2N waves, wave-tile 64x64
    int ln15 = lane & 15, lq = lane >> 4;

    const ushort_t* YTb = yt + ((size_t)(b_ * NC * NO) << 11);
    const char* shc = (const char*)sh;
    int o0 = ob * 128;

    // hoisted per-lane constants -------------------------------------------
    int s0l = (lq ^ (ln15 & 7)) * 16;           // swizzled 16B slot, kk=0 (bytes)
    int s1l = ((4 + lq) ^ (ln15 & 7)) * 16;     // kk=1
    int aBase = (wr * 64 + ln15) * 128;         // A frag row base (bytes)
    int bBase = (wc * 64 + ln15) * 128;         // B frag row base (bytes)
    int dL  = tid * 8;                          // LDS dest elems (flat j adds 2048)
    int srow = tid >> 3, ssl = tid & 7;         // stage row/chunk for j=0

    auto stageA = [&](ushort_t* L, int tt, int c) {
#pragma unroll
        for (int jj = 0; jj < 4; ++jj) {
            int row = srow + jj * 32;
            int slot = 2 * pp + (row >> 6) - tt + 3;
            glds16(L + dL + jj * 2048,
                   Tb + (((size_t)(slot * NC + c)) << 12)
                      + (row & 63) * 64 + ((ssl ^ (row & 7)) * 8));
        }
    };
    auto stageB = [&](ushort_t* L, int tt, int c) {
#pragma unroll
        for (int jj = 0; jj < 4; ++jj) {
            int row = srow + jj * 32;
            glds16(L + dL + jj * 2048,
                   YTb + (((size_t)(c * NO + o0 + row)) << 11)
                       + tt * 64 + ((ssl ^ (row & 7)) * 8));
        }
    };
    auto stageU = [&](int u) {
        int tt = u / 48, c = u - tt * 48;
        stageA(sh + ((u & 1) << 13), tt, c);
        stageB(sh + 16384 + ((u & 1) << 13), tt, c);
    };

    f32x4 acc[4][4];
    f32x4 z = {0.f, 0.f, 0.f, 0.f};
#pragma unroll
    for (int mi = 0; mi < 4; ++mi)
#pragma unroll
        for (int ni = 0; ni < 4; ++ni) acc[mi][ni] = z;

    bf16x8 s0a[4], s0b[4], s1a[4], s1b[4];

    // prologue: stage u0, u0+1; confirm u0; load h0(u0) -> set0
    stageU(u0);
    stageU(u0 + 1);
    asm volatile("s_waitcnt vmcnt(8)" ::: "memory");
    asm volatile("s_barrier" ::: "memory");
    {
        const char* AB = shc + ((u0 & 1) << 14);
        const char* BB = shc + 32768 + ((u0 & 1) << 14);
        LOAD_SET(s0a, s0b, s0l, AB, BB);
    }

    for (int s = u0; s < u1; ++s) {
        const char* AB = shc + ((s & 1) << 14);
        const char* BB = shc + 32768 + ((s & 1) << 14);

        // (1) reads h1 -> set1 (service overlaps h0 MFMAs)
        LOAD_SET(s1a, s1b, s1l, AB, BB);
        __builtin_amdgcn_sched_barrier(0);

        // (2) MFMA h0 (set0; loaded during previous tile)
        __builtin_amdgcn_s_setprio(1);
        MFMA_SET(s0a, s0b);
        __builtin_amdgcn_s_setprio(0);

        // (3) buffer-release + stage(s+1)-landed
        asm volatile("s_waitcnt lgkmcnt(0)" ::: "memory");
        asm volatile("s_waitcnt vmcnt(0)" ::: "memory");
        __builtin_amdgcn_sched_barrier(0);
        // (4) the one barrier per K-tile
        asm volatile("s_barrier" ::: "memory");

        // (5) stage s+2 into buf(s&1)
        if (s + 2 < u1) stageU(s + 2);

        // (6) reads h0(s+1) -> set0 (service overlaps h1 MFMAs)
        if (s + 1 < u1) {
            const char* AB2 = shc + (((s + 1) & 1) << 14);
            const char* BB2 = shc + 32768 + (((s + 1) & 1) << 14);
            LOAD_SET(s0a, s0b, s0l, AB2, BB2);
        }
        __builtin_amdgcn_sched_barrier(0);

        // (7) MFMA h1 (set1)
        __builtin_amdgcn_s_setprio(1);
        MFMA_SET(s1a, s1b);
        __builtin_amdgcn_s_setprio(0);
        __builtin_amdgcn_sched_barrier(0);
    }

    float* outp = out + (((size_t)b_ * SL) + (size_t)pp * 128) * NO + o0;
#pragma unroll
    for (int mi = 0; mi < 4; ++mi)
#pragma unroll
        for (int ni = 0; ni < 4; ++ni) {
            int l = wr * 64 + mi * 16 + lq * 4;
            int o = wc * 64 + ni * 16 + ln15;
#pragma unroll
            for (int r = 0; r < 4; ++r)
                atomicAdd(&outp[(size_t)(l + r) * NO + o], acc[mi][ni][r]);
        }
}

extern "C" void kernel_launch(void* const* d_in, const int* in_sizes, int n_in,
                              void* d_out, int out_size, void* d_ws, size_t ws_size,
                              hipStream_t stream) {
    const float* x   = (const float*)d_in[0];
    const float* phi = (const float*)d_in[1];
    const float* Mp  = (const float*)d_in[2];
    const float* Mm  = (const float*)d_in[3];
    float* out = (float*)d_out;

    if (ws_size < WS_NEED) return;

    char* ws = (char*)d_ws;
    ushort_t* T  = (ushort_t*)(ws + OFF_T);
    ushort_t* MT = (ushort_t*)(ws + OFF_MT);
    ushort_t* XB = (ushort_t*)(ws + OFF_XB);
    ushort_t* YT = (ushort_t*)(ws + OFF_YT);

    hipMemsetAsync(d_out, 0, (size_t)out_size * sizeof(float), stream);
    k_prep<<<dim3(2212), dim3(256), 0, stream>>>(x, phi, Mp, Mm, XB, MT, T);
    k_gemm1<<<dim3(96, 32), dim3(256), 0, stream>>>(XB, MT, YT);
    k_conv4<<<dim3(1024), dim3(256), 0, stream>>>(T, YT, out);
}

// Round 11
// 180.588 us; speedup vs baseline: 1.3735x; 1.3735x over previous
//
#include <hip/hip_runtime.h>
#include <hip/hip_bf16.h>

#define SL 2048
#define NK 24
#define NI 256
#define NO 256
#define NB 2
#define NC 48
#define TD 64

typedef __bf16 bf16x8 __attribute__((ext_vector_type(8)));
typedef float f32x4 __attribute__((ext_vector_type(4)));
typedef unsigned short u16x8 __attribute__((ext_vector_type(8)));
typedef unsigned short ushort_t;
typedef unsigned int u32;

// workspace layout (bytes)
// G table: 8 shift-copies x 48 ch x 2304 (reversed F, zero-padded):
//   G[p][c][j] = F[2047-(j+p), c]  (0 outside [0,2048))
#define OFF_G   0ull
#define SZ_G    (8ull*48*2304*2)          // 1,769,472
#define OFF_MT  (OFF_G + 14155776ull)     // keep old offsets (G fits in old T slot)
#define SZ_MT   (48ull*256*256*2)
#define OFF_XB  (OFF_MT + SZ_MT)          // x bf16 [2][2048][256]
#define SZ_XB   (2ull*2048*256*2)
#define OFF_YT  (OFF_XB + SZ_XB)          // Y_T [2][48][256][2048] bf16 ([b][c][o][t])
#define SZ_YT   (2ull*48*256*2048*2)
#define WS_NEED (OFF_YT + SZ_YT)

__device__ __forceinline__ unsigned short f2bf(float f) {
    unsigned int u = __float_as_uint(f);
    unsigned int r = (u + 0x7FFFu + ((u >> 16) & 1u)) >> 16;
    return (unsigned short)r;
}

__device__ __forceinline__ void glds16(ushort_t* l, const ushort_t* g) {
    __builtin_amdgcn_global_load_lds((const __attribute__((address_space(1))) u32*)g,
                                     (__attribute__((address_space(3))) u32*)l, 16, 0, 0);
}

// ---- kernel P: fused prep (cvt_x | mt | G-table), blockIdx-partitioned ---
// [0,1024): x f32->bf16 ; [1024,1792): M transpose ; [1792,2176): G table
__global__ __launch_bounds__(256) void k_prep(const float* __restrict__ x,
                                              const float* __restrict__ phi,
                                              const float* __restrict__ Mp,
                                              const float* __restrict__ Mm,
                                              ushort_t* __restrict__ xb,
                                              ushort_t* __restrict__ mt,
                                              ushort_t* __restrict__ G) {
    __shared__ float tile[64][65];
    int blk = blockIdx.x, tid = threadIdx.x;
    if (blk < 1024) {
        int i = blk * 256 + tid;                 // float4 index, 262144 total
        float4 v = reinterpret_cast<const float4*>(x)[i];
        ushort4 o;
        o.x = f2bf(v.x); o.y = f2bf(v.y); o.z = f2bf(v.z); o.w = f2bf(v.w);
        reinterpret_cast<ushort4*>(xb)[i] = o;
    } else if (blk < 1792) {
        int id = blk - 1024;                     // 768 = 48 c x 4 it x 4 ot
        int c = id >> 4, it = (id >> 2) & 3, ot = id & 3;
        int k = c >> 1;
        const float* M = (c & 1) ? Mm : Mp;
        int col = tid & 63, rq = tid >> 6;
        for (int rr = 0; rr < 64; rr += 4) {
            int i = rr + rq;
            tile[i][col] = M[((k * NI) + (it * 64 + i)) * NO + ot * 64 + col];
        }
        __syncthreads();
        for (int rr = 0; rr < 64; rr += 4) {
            int o = rr + rq;
            mt[((c * NO) + (ot * 64 + o)) * NI + it * 64 + col] = f2bf(tile[col][o]);
        }
    } else {
        int id = blk - 1792;                     // 384 = 8 p x 48 c
        int p = id / 48, c = id - p * 48;
        int k = c >> 1, odd = c & 1;
        ushort_t* Gpc = G + (size_t)(p * 48 + c) * 2304;
#pragma unroll
        for (int i = 0; i < 9; ++i) {
            int j = i * 256 + tid;
            int s = 2047 - (j + p);
            float v = 0.f;
            if (s >= 0 && s < SL) {
                v = phi[s * NK + k];
                if (odd && (s & 1)) v = -v;
            }
            Gpc[j] = f2bf(v);
        }
    }
}

// ---- kernel 2: Y_T[b][c][o][t] = sum_i x[b,t,i] * M_c[i,o] (known-good) --
__global__ __launch_bounds__(256, 4) void k_gemm1(const ushort_t* __restrict__ XB,
                                                  const ushort_t* __restrict__ MT,
                                                  ushort_t* __restrict__ yt) {
    __shared__ ushort_t sh[17408];
    int nb_ = blockIdx.x;
    int rb  = blockIdx.y;
    int n0 = nb_ * 128;
    int tid = threadIdx.x, lane = tid & 63, wid = tid >> 6;
    int wr = wid >> 1, wc = wid & 1;
    int ln15 = lane & 15, lq = lane >> 4;
    int swz = lq ^ ((ln15 >> 1) & 3);

    const ushort_t* Arow = XB + (size_t)(rb * 128) * 256;
    const ushort_t* Brow = MT + (size_t)n0 * 256;

    auto stage = [&](int bufsel, int s) {
        ushort_t* L = sh + bufsel * 8192;
        int k0 = s * 32;
#pragma unroll
        for (int jj = 0; jj < 2; ++jj) {
            int flat = tid + jj * 256;
            int row = flat >> 2;
            int k8s = (flat & 3) ^ ((flat >> 3) & 3);
            glds16(L + flat * 8, Arow + row * 256 + k0 + k8s * 8);
        }
#pragma unroll
        for (int jj = 0; jj < 2; ++jj) {
            int flat = tid + jj * 256;
            int row = flat >> 2;
            int k8s = (flat & 3) ^ ((flat >> 3) & 3);
            glds16(L + 4096 + flat * 8, Brow + row * 256 + k0 + k8s * 8);
        }
    };

    f32x4 acc[4][4];
    f32x4 z = {0.f, 0.f, 0.f, 0.f};
#pragma unroll
    for (int mi = 0; mi < 4; ++mi)
#pragma unroll
        for (int ni = 0; ni < 4; ++ni) acc[mi][ni] = z;

    stage(0, 0);
    __syncthreads();
    for (int s = 0; s < 8; ++s) {
        int cur = s & 1;
        if (s < 7) stage(cur ^ 1, s + 1);
        const ushort_t* Ab = sh + cur * 8192;
        const ushort_t* Bb = Ab + 4096;
        bf16x8 af[4], bfr[4];
#pragma unroll
        for (int mi = 0; mi < 4; ++mi)
            af[mi] = *reinterpret_cast<const bf16x8*>(Ab + (wr * 64 + mi * 16 + ln15) * 32 + swz * 8);
#pragma unroll
        for (int ni = 0; ni < 4; ++ni)
            bfr[ni] = *reinterpret_cast<const bf16x8*>(Bb + (wc * 64 + ni * 16 + ln15) * 32 + swz * 8);
#pragma unroll
        for (int mi = 0; mi < 4; ++mi)
#pragma unroll
            for (int ni = 0; ni < 4; ++ni)
                acc[mi][ni] = __builtin_amdgcn_mfma_f32_16x16x32_bf16(af[mi], bfr[ni], acc[mi][ni], 0, 0, 0);
        __syncthreads();
    }

    ushort_t* OT = sh;  // [128 n][136]
#pragma unroll
    for (int mi = 0; mi < 4; ++mi)
#pragma unroll
        for (int ni = 0; ni < 4; ++ni) {
            int t_loc = wr * 64 + mi * 16 + lq * 4;
            int n_loc = wc * 64 + ni * 16 + ln15;
            ushort4 pk;
            pk.x = f2bf(acc[mi][ni][0]);
            pk.y = f2bf(acc[mi][ni][1]);
            pk.z = f2bf(acc[mi][ni][2]);
            pk.w = f2bf(acc[mi][ni][3]);
            *reinterpret_cast<ushort4*>(OT + n_loc * 136 + t_loc) = pk;
        }
    __syncthreads();
    int b = rb >> 4, t0 = (rb & 15) * 128;
#pragma unroll
    for (int jj = 0; jj < 8; ++jj) {
        int flat = tid + jj * 256;
        int n_loc = flat >> 4, te = (flat & 15) * 8;
        int nn = n0 + n_loc;
        int c = nn >> 8, o = nn & 255;
        *reinterpret_cast<u16x8*>(yt + ((size_t)(b * NC + c) * NO + o) * SL + t0 + te) =
            *reinterpret_cast<const u16x8*>(OT + n_loc * 136 + te);
    }
}

// ---- kernel 3: conv (round-7 schedule verbatim); A staged from the
// L2-resident G table instead of the 13.8MB Toeplitz bank.
// A-chunk (8 consecutive ti, descending s) = 8 consecutive elems of G;
// shift-copy rho=(7-srow)&7 makes every source 16B-aligned, thread-constant.
#define LOAD_SET(SA, SB, SLOT, AB, BB) do {                                        \
    _Pragma("unroll") for (int m = 0; m < 8; ++m)                                  \
        SA[m] = *(const bf16x8*)((AB) + aBase + (SLOT) + m * 2048);                \
    _Pragma("unroll") for (int n2 = 0; n2 < 4; ++n2)                               \
        SB[n2] = *(const bf16x8*)((BB) + bBase + (SLOT) + n2 * 2048);              \
} while (0)

#define MFMA_SET(SA, SB) do {                                                      \
    _Pragma("unroll") for (int m = 0; m < 8; ++m)                                  \
    _Pragma("unroll") for (int n2 = 0; n2 < 4; ++n2)                               \
        acc[m][n2] = __builtin_amdgcn_mfma_f32_16x16x32_bf16(                      \
            SA[m], SB[n2], acc[m][n2], 0, 0, 0);                                   \
} while (0)

__global__ __launch_bounds__(512, 2) void k_conv8(const ushort_t* __restrict__ Gb,
                                                  const ushort_t* __restrict__ yt,
                                                  float* __restrict__ out) {
    __shared__ ushort_t sh[65536];   // A bufs @ bytes 0/32768 ; B bufs @ 65536/98304

    int blk = blockIdx.x;                       // 256
    int orig = (blk & 7) * 32 + (blk >> 3);     // XCD-chunked bijective (256%8==0)
    const int NBt[8] = {4, 7, 11, 14, 18, 21, 25, 28};   // sum = 128 per batch
    int b_ = orig >> 7;
    int j = orig & 127;
    int pp = 0, base = 0;
    while (pp < 7 && j >= base + NBt[pp]) { base += NBt[pp]; ++pp; }
    int idx = j - base, n = NBt[pp];
    int U = 192 * (pp + 1);                     // K-tiles in this group
    int u0 = idx * U / n, u1 = (idx + 1) * U / n;

    int tid = threadIdx.x, lane = tid & 63, wid = tid >> 6;
    int wr = wid >> 2, wc = wid & 3;            // 2M x 4N waves
    int ln15 = lane & 15, lq = lane >> 4;

    const ushort_t* YTb = yt + ((size_t)(b_ * NC * NO) << 11);
    const char* shc = (const char*)sh;

    // hoisted per-lane constants -------------------------------------------
    int s0l = (lq ^ (ln15 & 7)) * 16;           // swizzled 16B slot, kk=0 (bytes)
    int s1l = ((4 + lq) ^ (ln15 & 7)) * 16;     // kk=1
    int aBase = (wr * 128 + ln15) * 128;        // A frag row base (bytes)
    int bBase = (wc * 64 + ln15) * 128;         // B frag row base (bytes)
    int gBl = ((tid >> 3) & 31) * 2048 + ((tid & 7) ^ ((tid >> 3) & 7)) * 8; // elems
    int w2  = wid >> 2;
    int dAl = tid * 8;                                        // A LDS dest (elems)
    int dBl = w2 * 4096 + (wid & 3) * 512 + lane * 8;         // B LDS dest (elems)
    // A source in G: m0 = 2239 - 64*slot - srow + ti0 ; rho = (7-srow)&7
    int srow = tid >> 3;
    int ti0 = ((tid & 7) ^ (srow & 7)) * 8;
    int rho = (7 - srow) & 7;
    // aG0 + c*2304 - 64*slot  (elements into G)
    int aG0 = rho * 48 * 2304 + 2239 - srow + ti0 - rho;

    auto stageA = [&](ushort_t* L, int tt, int c) {
        int aGc = aG0 + c * 2304 - 64 * (4 * pp - tt + 3);
#pragma unroll
        for (int jj = 0; jj < 2; ++jj)
#pragma unroll
            for (int qm = 0; qm < 2; ++qm)
                glds16(L + jj * 8192 + qm * 4096 + dAl,
                       Gb + aGc - 64 * (jj * 2 + qm));
    };
    auto stageB = [&](ushort_t* L, int tt, int c) {
#pragma unroll
        for (int jj = 0; jj < 2; ++jj)
#pragma unroll
            for (int qn = 0; qn < 2; ++qn) {
                int rowS = (jj * 2 + w2) * 64 + qn * 32;
                glds16(L + jj * 8192 + qn * 2048 + dBl,
                       YTb + (((size_t)(c * NO + rowS)) << 11) + tt * 64 + gBl);
            }
    };
    auto stageU = [&](int u) {
        int tt = u / 48, c = u - tt * 48;
        stageA(sh + ((u & 1) << 14), tt, c);
        stageB(sh + 32768 + ((u & 1) << 14), tt, c);
    };

    f32x4 acc[8][4];
    f32x4 z = {0.f, 0.f, 0.f, 0.f};
#pragma unroll
    for (int mi = 0; mi < 8; ++mi)
#pragma unroll
        for (int ni = 0; ni < 4; ++ni) acc[mi][ni] = z;

    bf16x8 s0a[8], s0b[4], s1a[8], s1b[4];

    // prologue: stage u0, u0+1; confirm u0; load h0(u0) -> set0
    stageU(u0);
    stageU(u0 + 1);
    asm volatile("s_waitcnt vmcnt(8)" ::: "memory");
    asm volatile("s_barrier" ::: "memory");
    {
        const char* AB = shc + ((u0 & 1) << 15);
        const char* BB = shc + 65536 + ((u0 & 1) << 15);
        LOAD_SET(s0a, s0b, s0l, AB, BB);
    }

    for (int s = u0; s < u1; ++s) {
        const char* AB = shc + ((s & 1) << 15);
        const char* BB = shc + 65536 + ((s & 1) << 15);

        // (1) reads h1 -> set1 (service overlaps h0 MFMAs)
        LOAD_SET(s1a, s1b, s1l, AB, BB);
        __builtin_amdgcn_sched_barrier(0);

        // (2) MFMA h0 (set0; loaded during previous tile — compiler-precise lgkm)
        __builtin_amdgcn_s_setprio(1);
        MFMA_SET(s0a, s0b);
        __builtin_amdgcn_s_setprio(0);

        // (3) buffer-release: all my LDS reads of buf(s&1) done; my stage-writes
        //     for s+1 (issued last tile) landed.
        asm volatile("s_waitcnt lgkmcnt(0)" ::: "memory");
        asm volatile("s_waitcnt vmcnt(0)" ::: "memory");
        __builtin_amdgcn_sched_barrier(0);
        // (4) the one barrier: after it, buf(s&1) is writable, buf(s+1) readable
        asm volatile("s_barrier" ::: "memory");

        // (5) stage s+2 into buf(s&1)
        if (s + 2 < u1) stageU(s + 2);

        // (6) reads h0(s+1) -> set0 (service overlaps h1 MFMAs)
        if (s + 1 < u1) {
            const char* AB2 = shc + (((s + 1) & 1) << 15);
            const char* BB2 = shc + 65536 + (((s + 1) & 1) << 15);
            LOAD_SET(s0a, s0b, s0l, AB2, BB2);
        }
        __builtin_amdgcn_sched_barrier(0);

        // (7) MFMA h1 (set1)
        __builtin_amdgcn_s_setprio(1);
        MFMA_SET(s1a, s1b);
        __builtin_amdgcn_s_setprio(0);
        __builtin_amdgcn_sched_barrier(0);
    }

    float* outp = out + (((size_t)b_ * SL) + (size_t)pp * 256) * NO;
#pragma unroll
    for (int mi = 0; mi < 8; ++mi)
#pragma unroll
        for (int ni = 0; ni < 4; ++ni) {
            int l = wr * 128 + mi * 16 + lq * 4;
            int o = wc * 64 + ni * 16 + ln15;
#pragma unroll
            for (int r = 0; r < 4; ++r)
                atomicAdd(&outp[(size_t)(l + r) * NO + o], acc[mi][ni][r]);
        }
}

extern "C" void kernel_launch(void* const* d_in, const int* in_sizes, int n_in,
                              void* d_out, int out_size, void* d_ws, size_t ws_size,
                              hipStream_t stream) {
    const float* x   = (const float*)d_in[0];
    const float* phi = (const float*)d_in[1];
    const float* Mp  = (const float*)d_in[2];
    const float* Mm  = (const float*)d_in[3];
    float* out = (float*)d_out;

    if (ws_size < WS_NEED) return;

    char* ws = (char*)d_ws;
    ushort_t* G  = (ushort_t*)(ws + OFF_G);
    ushort_t* MT = (ushort_t*)(ws + OFF_MT);
    ushort_t* XB = (ushort_t*)(ws + OFF_XB);
    ushort_t* YT = (ushort_t*)(ws + OFF_YT);

    hipMemsetAsync(d_out, 0, (size_t)out_size * sizeof(float), stream);
    k_prep<<<dim3(2176), dim3(256), 0, stream>>>(x, phi, Mp, Mm, XB, MT, G);
    k_gemm1<<<dim3(96, 32), dim3(256), 0, stream>>>(XB, MT, YT);
    k_conv8<<<dim3(256), dim3(512), 0, stream>>>(G, YT, out);
}

// Round 12
// 177.975 us; speedup vs baseline: 1.3937x; 1.0147x over previous
//
#include <hip/hip_runtime.h>
#include <hip/hip_bf16.h>

#define SL 2048
#define NK 24
#define NI 256
#define NO 256
#define NB 2
#define NC 48
#define TD 64

typedef __bf16 bf16x8 __attribute__((ext_vector_type(8)));
typedef float f32x4 __attribute__((ext_vector_type(4)));
typedef unsigned short u16x8 __attribute__((ext_vector_type(8)));
typedef unsigned short ushort_t;
typedef unsigned int u32;

// workspace layout (bytes)
// G table: 8 shift-copies x 48 ch x 2304 (reversed F, zero-padded):
//   G[p][c][j] = F[2047-(j+p), c]  (0 outside [0,2048))
#define OFF_G   0ull
#define SZ_G    (8ull*48*2304*2)          // 1,769,472
#define OFF_MT  (OFF_G + 14155776ull)
#define SZ_MT   (48ull*256*256*2)
#define OFF_XB  (OFF_MT + SZ_MT)          // x bf16 [2][2048][256]
#define SZ_XB   (2ull*2048*256*2)
#define OFF_YT  (OFF_XB + SZ_XB)          // YT2 [2][48][32 tt][256 o][64 t'] bf16
#define SZ_YT   (2ull*48*256*2048*2)
#define WS_NEED (OFF_YT + SZ_YT)

__device__ __forceinline__ unsigned short f2bf(float f) {
    unsigned int u = __float_as_uint(f);
    unsigned int r = (u + 0x7FFFu + ((u >> 16) & 1u)) >> 16;
    return (unsigned short)r;
}

__device__ __forceinline__ void glds16(ushort_t* l, const ushort_t* g) {
    __builtin_amdgcn_global_load_lds((const __attribute__((address_space(1))) u32*)g,
                                     (__attribute__((address_space(3))) u32*)l, 16, 0, 0);
}

// ---- kernel P: fused prep (cvt_x | mt | G-table), blockIdx-partitioned ---
__global__ __launch_bounds__(256) void k_prep(const float* __restrict__ x,
                                              const float* __restrict__ phi,
                                              const float* __restrict__ Mp,
                                              const float* __restrict__ Mm,
                                              ushort_t* __restrict__ xb,
                                              ushort_t* __restrict__ mt,
                                              ushort_t* __restrict__ G) {
    __shared__ float tile[64][65];
    int blk = blockIdx.x, tid = threadIdx.x;
    if (blk < 1024) {
        int i = blk * 256 + tid;                 // float4 index, 262144 total
        float4 v = reinterpret_cast<const float4*>(x)[i];
        ushort4 o;
        o.x = f2bf(v.x); o.y = f2bf(v.y); o.z = f2bf(v.z); o.w = f2bf(v.w);
        reinterpret_cast<ushort4*>(xb)[i] = o;
    } else if (blk < 1792) {
        int id = blk - 1024;                     // 768 = 48 c x 4 it x 4 ot
        int c = id >> 4, it = (id >> 2) & 3, ot = id & 3;
        int k = c >> 1;
        const float* M = (c & 1) ? Mm : Mp;
        int col = tid & 63, rq = tid >> 6;
        for (int rr = 0; rr < 64; rr += 4) {
            int i = rr + rq;
            tile[i][col] = M[((k * NI) + (it * 64 + i)) * NO + ot * 64 + col];
        }
        __syncthreads();
        for (int rr = 0; rr < 64; rr += 4) {
            int o = rr + rq;
            mt[((c * NO) + (ot * 64 + o)) * NI + it * 64 + col] = f2bf(tile[col][o]);
        }
    } else {
        int id = blk - 1792;                     // 384 = 8 p x 48 c
        int p = id / 48, c = id - p * 48;
        int k = c >> 1, odd = c & 1;
        ushort_t* Gpc = G + (size_t)(p * 48 + c) * 2304;
#pragma unroll
        for (int i = 0; i < 9; ++i) {
            int j = i * 256 + tid;
            int s = 2047 - (j + p);
            float v = 0.f;
            if (s >= 0 && s < SL) {
                v = phi[s * NK + k];
                if (odd && (s & 1)) v = -v;
            }
            Gpc[j] = f2bf(v);
        }
    }
}

// ---- kernel 2: Y -> YT2 [b][c][tt][o][t'] (contiguous 32KB K-units) -----
__global__ __launch_bounds__(256, 4) void k_gemm1(const ushort_t* __restrict__ XB,
                                                  const ushort_t* __restrict__ MT,
                                                  ushort_t* __restrict__ yt) {
    __shared__ ushort_t sh[17408];
    int nb_ = blockIdx.x;
    int rb  = blockIdx.y;
    int n0 = nb_ * 128;
    int tid = threadIdx.x, lane = tid & 63, wid = tid >> 6;
    int wr = wid >> 1, wc = wid & 1;
    int ln15 = lane & 15, lq = lane >> 4;
    int swz = lq ^ ((ln15 >> 1) & 3);

    const ushort_t* Arow = XB + (size_t)(rb * 128) * 256;
    const ushort_t* Brow = MT + (size_t)n0 * 256;

    auto stage = [&](int bufsel, int s) {
        ushort_t* L = sh + bufsel * 8192;
        int k0 = s * 32;
#pragma unroll
        for (int jj = 0; jj < 2; ++jj) {
            int flat = tid + jj * 256;
            int row = flat >> 2;
            int k8s = (flat & 3) ^ ((flat >> 3) & 3);
            glds16(L + flat * 8, Arow + row * 256 + k0 + k8s * 8);
        }
#pragma unroll
        for (int jj = 0; jj < 2; ++jj) {
            int flat = tid + jj * 256;
            int row = flat >> 2;
            int k8s = (flat & 3) ^ ((flat >> 3) & 3);
            glds16(L + 4096 + flat * 8, Brow + row * 256 + k0 + k8s * 8);
        }
    };

    f32x4 acc[4][4];
    f32x4 z = {0.f, 0.f, 0.f, 0.f};
#pragma unroll
    for (int mi = 0; mi < 4; ++mi)
#pragma unroll
        for (int ni = 0; ni < 4; ++ni) acc[mi][ni] = z;

    stage(0, 0);
    __syncthreads();
    for (int s = 0; s < 8; ++s) {
        int cur = s & 1;
        if (s < 7) stage(cur ^ 1, s + 1);
        const ushort_t* Ab = sh + cur * 8192;
        const ushort_t* Bb = Ab + 4096;
        bf16x8 af[4], bfr[4];
#pragma unroll
        for (int mi = 0; mi < 4; ++mi)
            af[mi] = *reinterpret_cast<const bf16x8*>(Ab + (wr * 64 + mi * 16 + ln15) * 32 + swz * 8);
#pragma unroll
        for (int ni = 0; ni < 4; ++ni)
            bfr[ni] = *reinterpret_cast<const bf16x8*>(Bb + (wc * 64 + ni * 16 + ln15) * 32 + swz * 8);
#pragma unroll
        for (int mi = 0; mi < 4; ++mi)
#pragma unroll
            for (int ni = 0; ni < 4; ++ni)
                acc[mi][ni] = __builtin_amdgcn_mfma_f32_16x16x32_bf16(af[mi], bfr[ni], acc[mi][ni], 0, 0, 0);
        __syncthreads();
    }

    ushort_t* OT = sh;  // [128 n][136]
#pragma unroll
    for (int mi = 0; mi < 4; ++mi)
#pragma unroll
        for (int ni = 0; ni < 4; ++ni) {
            int t_loc = wr * 64 + mi * 16 + lq * 4;
            int n_loc = wc * 64 + ni * 16 + ln15;
            ushort4 pk;
            pk.x = f2bf(acc[mi][ni][0]);
            pk.y = f2bf(acc[mi][ni][1]);
            pk.z = f2bf(acc[mi][ni][2]);
            pk.w = f2bf(acc[mi][ni][3]);
            *reinterpret_cast<ushort4*>(OT + n_loc * 136 + t_loc) = pk;
        }
    __syncthreads();
    int b = rb >> 4;
    int tt0 = (rb & 15) * 2;
#pragma unroll
    for (int jj = 0; jj < 8; ++jj) {
        int flat = tid + jj * 256;
        int n_loc = flat >> 4, te = (flat & 15) * 8;
        int nn = n0 + n_loc;
        int c = nn >> 8, o = nn & 255;
        int tt = tt0 + (te >> 6), tp = te & 63;
        *reinterpret_cast<u16x8*>(yt + ((((size_t)(b * NC + c) * 32 + tt) << 8) + o) * 64 + tp) =
            *reinterpret_cast<const u16x8*>(OT + n_loc * 136 + te);
    }
}

// ---- kernel 3: conv (round-7 schedule verbatim); A from L2-resident G,
// B from contiguous YT2 K-units (1KB-contiguous wave loads).
#define LOAD_SET(SA, SB, SLOT, AB, BB) do {                                        \
    _Pragma("unroll") for (int m = 0; m < 8; ++m)                                  \
        SA[m] = *(const bf16x8*)((AB) + aBase + (SLOT) + m * 2048);                \
    _Pragma("unroll") for (int n2 = 0; n2 < 4; ++n2)                               \
        SB[n2] = *(const bf16x8*)((BB) + bBase + (SLOT) + n2 * 2048);              \
} while (0)

#define MFMA_SET(SA, SB) do {                                                      \
    _Pragma("unroll") for (int m = 0; m < 8; ++m)                                  \
    _Pragma("unroll") for (int n2 = 0; n2 < 4; ++n2)                               \
        acc[m][n2] = __builtin_amdgcn_mfma_f32_16x16x32_bf16(                      \
            SA[m], SB[n2], acc[m][n2], 0, 0, 0);                                   \
} while (0)

__global__ __launch_bounds__(512, 2) void k_conv8(const ushort_t* __restrict__ Gb,
                                                  const ushort_t* __restrict__ yt,
                                                  float* __restrict__ out) {
    __shared__ ushort_t sh[65536];   // A bufs @ bytes 0/32768 ; B bufs @ 65536/98304

    int blk = blockIdx.x;                       // 256
    int orig = (blk & 7) * 32 + (blk >> 3);     // XCD-chunked bijective (256%8==0)
    const int NBt[8] = {4, 7, 11, 14, 18, 21, 25, 28};   // sum = 128 per batch
    int b_ = orig >> 7;
    int j = orig & 127;
    int pp = 0, base = 0;
    while (pp < 7 && j >= base + NBt[pp]) { base += NBt[pp]; ++pp; }
    int idx = j - base, n = NBt[pp];
    int U = 192 * (pp + 1);                     // K-tiles in this group
    int u0 = idx * U / n, u1 = (idx + 1) * U / n;

    int tid = threadIdx.x, lane = tid & 63, wid = tid >> 6;
    int wr = wid >> 2, wc = wid & 3;            // 2M x 4N waves
    int ln15 = lane & 15, lq = lane >> 4;

    const ushort_t* YTb = yt + (size_t)b_ * NC * 32 * 16384;
    const char* shc = (const char*)sh;

    // hoisted per-lane constants -------------------------------------------
    int s0l = (lq ^ (ln15 & 7)) * 16;           // swizzled 16B slot, kk=0 (bytes)
    int s1l = ((4 + lq) ^ (ln15 & 7)) * 16;     // kk=1
    int aBase = (wr * 128 + ln15) * 128;        // A frag row base (bytes)
    int bBase = (wc * 64 + ln15) * 128;         // B frag row base (bytes)
    int w2  = wid >> 2;
    int dAl = tid * 8;                                        // A LDS dest (elems)
    int dBl = w2 * 4096 + (wid & 3) * 512 + lane * 8;         // B LDS dest (elems)
    // B global (contiguous unit): row = (tid>>3)&31 within 32-row stripe,
    // chunk = (tid&7)^(row&7); plus w2 fold (stripe base row w2*64)
    int gB2 = (((tid >> 3) & 31) + w2 * 64) * 64 + ((tid & 7) ^ ((tid >> 3) & 7)) * 8;
    // A source in G
    int srow = tid >> 3;
    int ti0 = ((tid & 7) ^ (srow & 7)) * 8;
    int rho = (7 - srow) & 7;
    int aG0 = rho * 48 * 2304 + 2239 - srow + ti0 - rho;

    auto stageA = [&](ushort_t* L, int tt, int c) {
        int aGc = aG0 + c * 2304 - 64 * (4 * pp - tt + 3);
#pragma unroll
        for (int jj = 0; jj < 2; ++jj)
#pragma unroll
            for (int qm = 0; qm < 2; ++qm)
                glds16(L + jj * 8192 + qm * 4096 + dAl,
                       Gb + aGc - 64 * (jj * 2 + qm));
    };
    auto stageB = [&](ushort_t* L, int tt, int c) {
        const ushort_t* Ub = YTb + (((size_t)(c * 32 + tt)) << 14) + gB2;
#pragma unroll
        for (int jj = 0; jj < 2; ++jj)
#pragma unroll
            for (int qn = 0; qn < 2; ++qn)
                glds16(L + jj * 8192 + qn * 2048 + dBl,
                       Ub + jj * 8192 + qn * 2048);
    };
    auto stageU = [&](int u) {
        int tt = u / 48, c = u - tt * 48;
        stageA(sh + ((u & 1) << 14), tt, c);
        stageB(sh + 32768 + ((u & 1) << 14), tt, c);
    };

    f32x4 acc[8][4];
    f32x4 z = {0.f, 0.f, 0.f, 0.f};
#pragma unroll
    for (int mi = 0; mi < 8; ++mi)
#pragma unroll
        for (int ni = 0; ni < 4; ++ni) acc[mi][ni] = z;

    bf16x8 s0a[8], s0b[4], s1a[8], s1b[4];

    // prologue: stage u0, u0+1; confirm u0; load h0(u0) -> set0
    stageU(u0);
    stageU(u0 + 1);
    asm volatile("s_waitcnt vmcnt(8)" ::: "memory");
    asm volatile("s_barrier" ::: "memory");
    {
        const char* AB = shc + ((u0 & 1) << 15);
        const char* BB = shc + 65536 + ((u0 & 1) << 15);
        LOAD_SET(s0a, s0b, s0l, AB, BB);
    }

    for (int s = u0; s < u1; ++s) {
        const char* AB = shc + ((s & 1) << 15);
        const char* BB = shc + 65536 + ((s & 1) << 15);

        // (1) reads h1 -> set1 (service overlaps h0 MFMAs)
        LOAD_SET(s1a, s1b, s1l, AB, BB);
        __builtin_amdgcn_sched_barrier(0);

        // (2) MFMA h0 (set0; loaded during previous tile — compiler-precise lgkm)
        __builtin_amdgcn_s_setprio(1);
        MFMA_SET(s0a, s0b);
        __builtin_amdgcn_s_setprio(0);

        // (3) buffer-release: all my LDS reads of buf(s&1) done; my stage-writes
        //     for s+1 (issued last tile) landed.
        asm volatile("s_waitcnt lgkmcnt(0)" ::: "memory");
        asm volatile("s_waitcnt vmcnt(0)" ::: "memory");
        __builtin_amdgcn_sched_barrier(0);
        // (4) the one barrier: after it, buf(s&1) is writable, buf(s+1) readable
        asm volatile("s_barrier" ::: "memory");

        // (5) stage s+2 into buf(s&1)
        if (s + 2 < u1) stageU(s + 2);

        // (6) reads h0(s+1) -> set0 (service overlaps h1 MFMAs)
        if (s + 1 < u1) {
            const char* AB2 = shc + (((s + 1) & 1) << 15);
            const char* BB2 = shc + 65536 + (((s + 1) & 1) << 15);
            LOAD_SET(s0a, s0b, s0l, AB2, BB2);
        }
        __builtin_amdgcn_sched_barrier(0);

        // (7) MFMA h1 (set1)
        __builtin_amdgcn_s_setprio(1);
        MFMA_SET(s1a, s1b);
        __builtin_amdgcn_s_setprio(0);
        __builtin_amdgcn_sched_barrier(0);
    }

    float* outp = out + (((size_t)b_ * SL) + (size_t)pp * 256) * NO;
#pragma unroll
    for (int mi = 0; mi < 8; ++mi)
#pragma unroll
        for (int ni = 0; ni < 4; ++ni) {
            int l = wr * 128 + mi * 16 + lq * 4;
            int o = wc * 64 + ni * 16 + ln15;
#pragma unroll
            for (int r = 0; r < 4; ++r)
                atomicAdd(&outp[(size_t)(l + r) * NO + o], acc[mi][ni][r]);
        }
}

extern "C" void kernel_launch(void* const* d_in, const int* in_sizes, int n_in,
                              void* d_out, int out_size, void* d_ws, size_t ws_size,
                              hipStream_t stream) {
    const float* x   = (const float*)d_in[0];
    const float* phi = (const float*)d_in[1];
    const float* Mp  = (const float*)d_in[2];
    const float* Mm  = (const float*)d_in[3];
    float* out = (float*)d_out;

    if (ws_size < WS_NEED) return;

    char* ws = (char*)d_ws;
    ushort_t* G  = (ushort_t*)(ws + OFF_G);
    ushort_t* MT = (ushort_t*)(ws + OFF_MT);
    ushort_t* XB = (ushort_t*)(ws + OFF_XB);
    ushort_t* YT = (ushort_t*)(ws + OFF_YT);

    hipMemsetAsync(d_out, 0, (size_t)out_size * sizeof(float), stream);
    k_prep<<<dim3(2176), dim3(256), 0, stream>>>(x, phi, Mp, Mm, XB, MT, G);
    k_gemm1<<<dim3(96, 32), dim3(256), 0, stream>>>(XB, MT, YT);
    k_conv8<<<dim3(256), dim3(512), 0, stream>>>(G, YT, out);
}